// Round 3
// baseline (214.119 us; speedup 1.0000x reference)
//
#include <hip/hip_runtime.h>

// Problem constants (RefinementLayer1): B=2, L=192, D=768, NC=4, H=256
#define LSEQ 192
#define DIM  768
#define NCASE 4
#define HID  256
#define BATCH 2

// tanh(x) = 1 - 2/(exp2(K*x)+1), K = 2*log2(e). K is pre-folded into lin and
// Bpack so the hot kernels compute tanh with only {exp2, add, rcp, fma}.
#define TANH_K 2.885390081777927f

typedef float  floatx4 __attribute__((ext_vector_type(4)));
typedef __bf16 bf16x8  __attribute__((ext_vector_type(8)));

// input already scaled by TANH_K
__device__ __forceinline__ float tanh_pre(float x) {
    float e = __builtin_amdgcn_exp2f(x);
    return 1.0f - 2.0f * __builtin_amdgcn_rcpf(e + 1.0f);
}

// ---------------------------------------------------------------------------
// MFMA fragment layouts (m89/m91-verified, 16x16x32 bf16):
//   A: lane holds A[m = lane&15][k = (lane>>4)*8 + j]   (bf16x8)
//   B: lane holds B[k = (lane>>4)*8 + j][h = lane&15]   (bf16x8)
//   C/D: lane reg holds D[row = (lane>>4)*4 + reg][col = lane&15]
// ---------------------------------------------------------------------------

// ---------------------------------------------------------------------------
// Kernel 0: pack everything (one launch, 3 jobs by linear thread id):
//  job A (t <  36864): seq -> seq_hi/seq_lo bf16 row-major (8 elems/thread)
//  job B (t < 159744): [Wp|Wa] -> W_hi/W_lo bf16 B-frags
//       frag u = (kc*80 + ctg)*64 + lane, k = kc*32+quad*8+j, col = ctg*16+col16
//  job C (rest):       Wmid/bmid -> Bpack bf16 B-frags, scaled by TANH_K
//       frag u = ((n*9 + kc)*16 + ct)*64 + lane; k rows 256..259 = bs rows,
//       k == 260 = bmid (paired with A=1), k > 260 = zero pad.
// ---------------------------------------------------------------------------
__global__ __launch_bounds__(256) void pack_all(
    const float* __restrict__ seq, const float* __restrict__ Wp,
    const float* __restrict__ Wa, const float* __restrict__ Wmid,
    const float* __restrict__ bmid,
    bf16x8* __restrict__ seq_hi, bf16x8* __restrict__ seq_lo,
    bf16x8* __restrict__ W_hi,   bf16x8* __restrict__ W_lo,
    bf16x8* __restrict__ Bpack)
{
    int t = blockIdx.x * 256 + threadIdx.x;
    if (t < 36864) {                       // ---- seq hi/lo, coalesced
        const float* s = seq + (size_t)t * 8;
        bf16x8 hi, lo;
        #pragma unroll
        for (int j = 0; j < 8; j++) {
            float v = s[j];
            __bf16 h = (__bf16)v;
            hi[j] = h;
            lo[j] = (__bf16)(v - (float)h);
        }
        seq_hi[t] = hi; seq_lo[t] = lo;
    } else if (t < 159744) {               // ---- [Wp|Wa] frags hi/lo
        int u = t - 36864;                 // (kc*80 + ctg)*64 + lane
        int lane = u & 63, f = u >> 6;
        int ctg = f % 80, kc = f / 80;
        int col16 = lane & 15, quad = lane >> 4;
        int col = ctg * 16 + col16;
        bf16x8 hi, lo;
        #pragma unroll
        for (int j = 0; j < 8; j++) {
            int k = kc * 32 + quad * 8 + j;
            float v = (col < 256) ? Wp[(size_t)k * HID + col]
                                  : Wa[(size_t)k * (NCASE * HID) + col - 256];
            __bf16 h = (__bf16)v;
            hi[j] = h;
            lo[j] = (__bf16)(v - (float)h);
        }
        W_hi[u] = hi; W_lo[u] = lo;
    } else {                               // ---- Wmid/bmid frags (TANH_K folded)
        int u = t - 159744;                // ((n*9+kc)*16+ct)*64 + lane
        int lane = u & 63, f = u >> 6;
        int ct = f & 15, nk = f >> 4;
        int kc = nk % 9, n = nk / 9;
        int col16 = lane & 15, quad = lane >> 4;
        int h = ct * 16 + col16;
        bf16x8 v;
        #pragma unroll
        for (int j = 0; j < 8; j++) {
            int k = kc * 32 + quad * 8 + j;
            float x;
            if (k < 260)       x = Wmid[(size_t)(n * 260 + k) * 256 + h];
            else if (k == 260) x = bmid[n * 256 + h];
            else               x = 0.0f;
            v[j] = (__bf16)(TANH_K * x);
        }
        Bpack[u] = v;
    }
}

// ---------------------------------------------------------------------------
// Kernel 1: lin[row, col] = TANH_K * (seq[row,:] @ [Wp|Wa][:, col] + bias)
// Barrier-free 1-wave blocks, MFMA bf16 with hi/lo split (hh + lh + hl) for
// near-fp32 accuracy. Grid (24 row-tiles of 16, 20 col-tiles of 64).
// ---------------------------------------------------------------------------
__global__ __launch_bounds__(64) void lin_mfma(
    const bf16x8* __restrict__ seq_hi, const bf16x8* __restrict__ seq_lo,
    const bf16x8* __restrict__ W_hi,   const bf16x8* __restrict__ W_lo,
    const float* __restrict__ bp, const float* __restrict__ ba,
    float* __restrict__ lin)
{
    const int rt = blockIdx.x;            // 24
    const int bn = blockIdx.y;            // 20
    const int lane  = threadIdx.x;
    const int quad  = lane >> 4;
    const int col16 = lane & 15;

    const int abase = (rt * 16 + col16) * 96 + quad;   // + kc*4 per chunk
    floatx4 acc[4] = {};                               // [ct]

    #pragma unroll
    for (int kc = 0; kc < 24; kc++) {
        bf16x8 ah = seq_hi[abase + kc * 4];
        bf16x8 al = seq_lo[abase + kc * 4];
        #pragma unroll
        for (int ct = 0; ct < 4; ct++) {
            int fu = (kc * 80 + bn * 4 + ct) * 64 + lane;
            bf16x8 bh = W_hi[fu];
            bf16x8 bl = W_lo[fu];
            acc[ct] = __builtin_amdgcn_mfma_f32_16x16x32_bf16(ah, bh, acc[ct], 0, 0, 0);
            acc[ct] = __builtin_amdgcn_mfma_f32_16x16x32_bf16(al, bh, acc[ct], 0, 0, 0);
            acc[ct] = __builtin_amdgcn_mfma_f32_16x16x32_bf16(ah, bl, acc[ct], 0, 0, 0);
        }
    }
    #pragma unroll
    for (int ct = 0; ct < 4; ct++) {
        const int col = bn * 64 + ct * 16 + col16;
        const float bias = (col < 256) ? bp[col] : ba[col - 256];
        #pragma unroll
        for (int reg = 0; reg < 4; reg++) {
            const int row = rt * 16 + quad * 4 + reg;
            lin[(size_t)row * 1280 + col] = TANH_K * (acc[ct][reg] + bias);
        }
    }
}

// ---------------------------------------------------------------------------
// Kernel 2: fused main — BARRIER-FREE. Block = 4 waves, 64 (p,a) rows, fixed
// (b,n). Wave w owns rows [w*16, w*16+16) x all 256 cols. A-fragments are
// generated tanh-in-register by the consuming lane (A layout: m=lane&15 is
// the row, k-slice by quad) — no LDS, no __syncthreads. B-frags are coalesced
// 1KB global loads from Bpack (L1-shared across the block's 4 waves).
// K-chunks 0..7 = tanh(hp+ha); chunk 8 = folded bs/bmid rows.
// Epilogue: tanh(acc).Wout, 16-lane shuffle reduce, direct global store.
// ---------------------------------------------------------------------------
__global__ __launch_bounds__(256, 3) void refine_main(
    const float* __restrict__ lin,        // [384][1280], pre-scaled by TANH_K
    const float* __restrict__ base_score, // [B][L][NC][L]
    const float* __restrict__ Wout,       // [NC][256]
    const bf16x8* __restrict__ Bpack,     // packed Wmid frags, 9 chunks
    float* __restrict__ out)              // [B][L][NC][L]
{
    const int bx = blockIdx.x;            // 576 = 24*24
    const int n  = blockIdx.y;
    const int b  = blockIdx.z;
    const int ptile = bx / 24, atile = bx % 24;
    const int p0 = ptile * 8, a0 = atile * 8;

    const int tid   = threadIdx.x;
    const int w     = tid >> 6;
    const int lane  = tid & 63;
    const int quad  = lane >> 4;
    const int col16 = lane & 15;

    // A-gen row for this lane: m = w*16 + col16 (A-frag m = lane&15)
    const int m_gen = w * 16 + col16;
    const int pg = p0 + (m_gen >> 3), ag = a0 + (m_gen & 7);
    const float* hp_ptr = lin + (size_t)(b * LSEQ + pg) * 1280 + quad * 8;
    const float* ha_ptr = lin + (size_t)(b * LSEQ + ag) * 1280 + 256 + n * 256 + quad * 8;
    const bf16x8* bfrag = Bpack + (size_t)n * (9 * 16 * 64) + lane;

    floatx4 acc[16] = {};                 // [ct] — 64 VGPRs

    floatx4 hp0 = *(const floatx4*)(hp_ptr);
    floatx4 hp1 = *(const floatx4*)(hp_ptr + 4);
    floatx4 ha0 = *(const floatx4*)(ha_ptr);
    floatx4 ha1 = *(const floatx4*)(ha_ptr + 4);

    #pragma unroll
    for (int kc = 0; kc < 8; kc++) {
        floatx4 s0 = hp0 + ha0;
        floatx4 s1 = hp1 + ha1;
        if (kc < 7) {                     // prefetch next chunk's A inputs
            hp0 = *(const floatx4*)(hp_ptr + (kc + 1) * 32);
            hp1 = *(const floatx4*)(hp_ptr + (kc + 1) * 32 + 4);
            ha0 = *(const floatx4*)(ha_ptr + (kc + 1) * 32);
            ha1 = *(const floatx4*)(ha_ptr + (kc + 1) * 32 + 4);
        }
        bf16x8 av;                        // A-frag, tanh in-register
        #pragma unroll
        for (int j = 0; j < 4; j++) av[j]     = (__bf16)tanh_pre(s0[j]);
        #pragma unroll
        for (int j = 0; j < 4; j++) av[4 + j] = (__bf16)tanh_pre(s1[j]);
        #pragma unroll
        for (int ct = 0; ct < 16; ct++)
            acc[ct] = __builtin_amdgcn_mfma_f32_16x16x32_bf16(
                av, bfrag[(kc * 16 + ct) * 64], acc[ct], 0, 0, 0);
    }

    // ---- chunk 8: A = [bs(4), 1, 0...], B = TANH_K*[Wmid[256:260]; bmid; 0]
    {
        bf16x8 av = {};
        if (quad == 0) {
            #pragma unroll
            for (int j = 0; j < 4; j++)
                av[j] = (__bf16)base_score[((size_t)(b * LSEQ + pg) * NCASE + j) * LSEQ + ag];
            av[4] = (__bf16)1.0f;
        }
        #pragma unroll
        for (int ct = 0; ct < 16; ct++)
            acc[ct] = __builtin_amdgcn_mfma_f32_16x16x32_bf16(
                av, bfrag[(8 * 16 + ct) * 64], acc[ct], 0, 0, 0);
    }

    // ---- epilogue: tanh(acc) . Wout, reduce over 16 cols within quad
    float rs[4] = {0.0f, 0.0f, 0.0f, 0.0f};
    #pragma unroll
    for (int ct = 0; ct < 16; ct++) {
        const float woc = Wout[n * 256 + ct * 16 + col16];
        #pragma unroll
        for (int reg = 0; reg < 4; reg++)
            rs[reg] += tanh_pre(acc[ct][reg]) * woc;
    }
    #pragma unroll
    for (int reg = 0; reg < 4; reg++) {
        rs[reg] += __shfl_xor(rs[reg], 1);
        rs[reg] += __shfl_xor(rs[reg], 2);
        rs[reg] += __shfl_xor(rs[reg], 4);
        rs[reg] += __shfl_xor(rs[reg], 8);
    }
    if (col16 == 0) {
        #pragma unroll
        for (int reg = 0; reg < 4; reg++) {
            const int r = w * 16 + quad * 4 + reg;     // D row = quad*4+reg
            const int p = p0 + (r >> 3), a = a0 + (r & 7);
            out[((size_t)(b * LSEQ + p) * NCASE + n) * LSEQ + a] = rs[reg];
        }
    }
}

// ---------------------------------------------------------------------------
extern "C" void kernel_launch(void* const* d_in, const int* in_sizes, int n_in,
                              void* d_out, int out_size, void* d_ws, size_t ws_size,
                              hipStream_t stream) {
    const float* seq  = (const float*)d_in[0];
    const float* bsc  = (const float*)d_in[1];
    const float* Wp   = (const float*)d_in[2];
    const float* bp   = (const float*)d_in[3];
    const float* Wa   = (const float*)d_in[4];
    const float* ba   = (const float*)d_in[5];
    const float* Wmid = (const float*)d_in[6];
    const float* bmid = (const float*)d_in[7];
    const float* Wout = (const float*)d_in[8];
    float* out = (float*)d_out;

    // workspace layout (16B-aligned):
    char* ws = (char*)d_ws;
    bf16x8* seq_hi = (bf16x8*)(ws);                    //   589,824 B
    bf16x8* seq_lo = (bf16x8*)(ws +  589824);          //   589,824 B
    bf16x8* W_hi   = (bf16x8*)(ws + 1179648);          // 1,966,080 B
    bf16x8* W_lo   = (bf16x8*)(ws + 3145728);          // 1,966,080 B
    bf16x8* Bpack  = (bf16x8*)(ws + 5111808);          //   589,824 B
    float*  lin    = (float*) (ws + 5701632);          // 1,966,080 B  (fp32)

    pack_all<<<768, 256, 0, stream>>>(seq, Wp, Wa, Wmid, bmid,
                                      seq_hi, seq_lo, W_hi, W_lo, Bpack);
    lin_mfma<<<dim3(24, 20), 64, 0, stream>>>(seq_hi, seq_lo, W_hi, W_lo,
                                              bp, ba, lin);
    refine_main<<<dim3(24 * 24, NCASE, BATCH), 256, 0, stream>>>(
        lin, bsc, Wout, Bpack, out);
}

// Round 4
// 162.924 us; speedup vs baseline: 1.3142x; 1.3142x over previous
//
#include <hip/hip_runtime.h>

// Problem constants (RefinementLayer1): B=2, L=192, D=768, NC=4, H=256
#define LSEQ 192
#define DIM  768
#define NCASE 4
#define HID  256
#define BATCH 2

// tanh(x) = 1 - 2/(exp2(K*x)+1), K = 2*log2(e). K is pre-folded into lin and
// Bpack so the hot kernels compute tanh with only {exp2, add, rcp, fma}.
#define TANH_K 2.885390081777927f

typedef float  floatx4 __attribute__((ext_vector_type(4)));
typedef __bf16 bf16x8  __attribute__((ext_vector_type(8)));

// input already scaled by TANH_K
__device__ __forceinline__ float tanh_pre(float x) {
    float e = __builtin_amdgcn_exp2f(x);
    return 1.0f - 2.0f * __builtin_amdgcn_rcpf(e + 1.0f);
}

// async global->LDS, 16B per lane. LDS dest = wave-uniform base + lane*16.
typedef __attribute__((address_space(1))) const unsigned int GlbU32;
typedef __attribute__((address_space(3))) unsigned int LdsU32;
__device__ __forceinline__ void stage16(const __bf16* g, __bf16* l) {
    __builtin_amdgcn_global_load_lds((GlbU32*)g, (LdsU32*)l, 16, 0, 0);
}

// ---------------------------------------------------------------------------
// MFMA fragment layouts (m89/m91-verified, 16x16x32 bf16):
//   A: lane holds A[m = lane&15][k = (lane>>4)*8 + j]   (bf16x8)
//   B: lane holds B[k = (lane>>4)*8 + j][h = lane&15]   (bf16x8)
//   C/D: lane reg holds D[row = (lane>>4)*4 + reg][col = lane&15]
// ---------------------------------------------------------------------------

// ---------------------------------------------------------------------------
// Kernel 0: pack everything (one launch, 3 jobs by linear thread id):
//  job A (t <  36864): seq -> seq_hi/seq_lo bf16 row-major (8 elems/thread)
//  job B (t < 159744): [Wp|Wa] -> W_hi/W_lo bf16 B-frags
//  job C (rest):       Wmid/bmid -> Bpack bf16 B-frags, scaled by TANH_K
//       frag u = ((n*9 + kc)*16 + ct)*64 + lane; k rows 256..259 = bs rows,
//       k == 260 = bmid (paired with A=1), k > 260 = zero pad.
// ---------------------------------------------------------------------------
__global__ __launch_bounds__(256) void pack_all(
    const float* __restrict__ seq, const float* __restrict__ Wp,
    const float* __restrict__ Wa, const float* __restrict__ Wmid,
    const float* __restrict__ bmid,
    bf16x8* __restrict__ seq_hi, bf16x8* __restrict__ seq_lo,
    bf16x8* __restrict__ W_hi,   bf16x8* __restrict__ W_lo,
    bf16x8* __restrict__ Bpack)
{
    int t = blockIdx.x * 256 + threadIdx.x;
    if (t < 36864) {                       // ---- seq hi/lo, coalesced
        const float* s = seq + (size_t)t * 8;
        bf16x8 hi, lo;
        #pragma unroll
        for (int j = 0; j < 8; j++) {
            float v = s[j];
            __bf16 h = (__bf16)v;
            hi[j] = h;
            lo[j] = (__bf16)(v - (float)h);
        }
        seq_hi[t] = hi; seq_lo[t] = lo;
    } else if (t < 159744) {               // ---- [Wp|Wa] frags hi/lo
        int u = t - 36864;                 // (kc*80 + ctg)*64 + lane
        int lane = u & 63, f = u >> 6;
        int ctg = f % 80, kc = f / 80;
        int col16 = lane & 15, quad = lane >> 4;
        int col = ctg * 16 + col16;
        bf16x8 hi, lo;
        #pragma unroll
        for (int j = 0; j < 8; j++) {
            int k = kc * 32 + quad * 8 + j;
            float v = (col < 256) ? Wp[(size_t)k * HID + col]
                                  : Wa[(size_t)k * (NCASE * HID) + col - 256];
            __bf16 h = (__bf16)v;
            hi[j] = h;
            lo[j] = (__bf16)(v - (float)h);
        }
        W_hi[u] = hi; W_lo[u] = lo;
    } else {                               // ---- Wmid/bmid frags (TANH_K folded)
        int u = t - 159744;                // ((n*9+kc)*16+ct)*64 + lane
        int lane = u & 63, f = u >> 6;
        int ct = f & 15, nk = f >> 4;
        int kc = nk % 9, n = nk / 9;
        int col16 = lane & 15, quad = lane >> 4;
        int h = ct * 16 + col16;
        bf16x8 v;
        #pragma unroll
        for (int j = 0; j < 8; j++) {
            int k = kc * 32 + quad * 8 + j;
            float x;
            if (k < 260)       x = Wmid[(size_t)(n * 260 + k) * 256 + h];
            else if (k == 260) x = bmid[n * 256 + h];
            else               x = 0.0f;
            v[j] = (__bf16)(TANH_K * x);
        }
        Bpack[u] = v;
    }
}

// ---------------------------------------------------------------------------
// Kernel 1: lin[row, col] = TANH_K * (seq[row,:] @ [Wp|Wa][:, col] + bias)
// Barrier-free 1-wave blocks, MFMA bf16 with hi/lo split (hh + lh + hl).
// ---------------------------------------------------------------------------
__global__ __launch_bounds__(64) void lin_mfma(
    const bf16x8* __restrict__ seq_hi, const bf16x8* __restrict__ seq_lo,
    const bf16x8* __restrict__ W_hi,   const bf16x8* __restrict__ W_lo,
    const float* __restrict__ bp, const float* __restrict__ ba,
    float* __restrict__ lin)
{
    const int rt = blockIdx.x;            // 24
    const int bn = blockIdx.y;            // 20
    const int lane  = threadIdx.x;
    const int quad  = lane >> 4;
    const int col16 = lane & 15;

    const int abase = (rt * 16 + col16) * 96 + quad;   // + kc*4 per chunk
    floatx4 acc[4] = {};                               // [ct]

    #pragma unroll
    for (int kc = 0; kc < 24; kc++) {
        bf16x8 ah = seq_hi[abase + kc * 4];
        bf16x8 al = seq_lo[abase + kc * 4];
        #pragma unroll
        for (int ct = 0; ct < 4; ct++) {
            int fu = (kc * 80 + bn * 4 + ct) * 64 + lane;
            bf16x8 bh = W_hi[fu];
            bf16x8 bl = W_lo[fu];
            acc[ct] = __builtin_amdgcn_mfma_f32_16x16x32_bf16(ah, bh, acc[ct], 0, 0, 0);
            acc[ct] = __builtin_amdgcn_mfma_f32_16x16x32_bf16(al, bh, acc[ct], 0, 0, 0);
            acc[ct] = __builtin_amdgcn_mfma_f32_16x16x32_bf16(ah, bl, acc[ct], 0, 0, 0);
        }
    }
    #pragma unroll
    for (int ct = 0; ct < 4; ct++) {
        const int col = bn * 64 + ct * 16 + col16;
        const float bias = (col < 256) ? bp[col] : ba[col - 256];
        #pragma unroll
        for (int reg = 0; reg < 4; reg++) {
            const int row = rt * 16 + quad * 4 + reg;
            lin[(size_t)row * 1280 + col] = TANH_K * (acc[ct][reg] + bias);
        }
    }
}

// ---------------------------------------------------------------------------
// Kernel 2: fused main. Block = 4 waves, 128 rows (16p x 8a) x 256 cols,
// fixed (b,n). Wave w owns rows [w*32, w*32+32) as TWO 16-row A-frags; the
// two rows a lane generates share the same 'a' index so ha loads once.
// A-frags: tanh in-register by the consuming lane (zero LDS, no A barrier).
// B-frags: non-redundant cooperative global_load_lds (wave w stages frags
// w*4..w*4+3), double-buffered, ONE barrier per chunk that only gates a copy
// issued a full chunk earlier. K: 8 tanh chunks + 1 folded bs/bmid chunk.
// Epilogue: tanh(acc).Wout, 16-lane shuffle reduce, direct global store.
// ---------------------------------------------------------------------------
__global__ __launch_bounds__(256, 2) void refine_main(
    const float* __restrict__ lin,        // [384][1280], pre-scaled by TANH_K
    const float* __restrict__ base_score, // [B][L][NC][L]
    const float* __restrict__ Wout,       // [NC][256]
    const __bf16* __restrict__ Bpack,     // packed Wmid frags (flat bf16)
    float* __restrict__ out)              // [B][L][NC][L]
{
    const int bx = blockIdx.x;            // 288 = 12*24
    const int n  = blockIdx.y;
    const int b  = blockIdx.z;
    const int ptile = bx / 24, atile = bx % 24;
    const int p0 = ptile * 16, a0 = atile * 8;

    const int tid   = threadIdx.x;
    const int w     = tid >> 6;
    const int lane  = tid & 63;
    const int quad  = lane >> 4;
    const int col16 = lane & 15;

    __shared__ __align__(16) __bf16 Blds[2][16 * 512];   // 32 KB, dbuf B-frags

    // A-gen rows: m0 = w*32+col16 (frag 0), m1 = m0+16 (frag 1, same a!)
    const int m0  = w * 32 + col16;
    const int pg0 = p0 + (m0 >> 3), pg1 = pg0 + 2, ag = a0 + (m0 & 7);
    const float* hp0_ptr = lin + (size_t)(b * LSEQ + pg0) * 1280 + quad * 8;
    const float* hp1_ptr = lin + (size_t)(b * LSEQ + pg1) * 1280 + quad * 8;
    const float* ha_ptr  = lin + (size_t)(b * LSEQ + ag) * 1280 + 256 + n * 256 + quad * 8;

    // B staging source for this wave (frags ct = w*4 .. w*4+3)
    const __bf16* bsrc = Bpack + ((size_t)(n * 9 * 16) + w * 4) * 512 + lane * 8;

    // prologue: stage chunk 0 into buf 0
    #pragma unroll
    for (int i = 0; i < 4; i++)
        stage16(bsrc + i * 512, &Blds[0][(w * 4 + i) * 512]);

    // A inputs for chunk 0
    floatx4 hp00 = *(const floatx4*)(hp0_ptr);
    floatx4 hp01 = *(const floatx4*)(hp0_ptr + 4);
    floatx4 hp10 = *(const floatx4*)(hp1_ptr);
    floatx4 hp11 = *(const floatx4*)(hp1_ptr + 4);
    floatx4 ha0  = *(const floatx4*)(ha_ptr);
    floatx4 ha1  = *(const floatx4*)(ha_ptr + 4);

    // base_score rows for the folded chunk 8
    float bsv0[4], bsv1[4];
    #pragma unroll
    for (int j = 0; j < 4; j++) {
        bsv0[j] = base_score[((size_t)(b * LSEQ + pg0) * NCASE + j) * LSEQ + ag];
        bsv1[j] = base_score[((size_t)(b * LSEQ + pg1) * NCASE + j) * LSEQ + ag];
    }

    floatx4 acc0[16] = {}, acc1[16] = {};   // rows [w*32,+16) / [w*32+16,+16)

    #pragma unroll
    for (int kc = 0; kc < 9; kc++) {
        __syncthreads();                  // buf[kc&1] staged a full chunk ago
        if (kc < 8) {                     // stage next chunk into other buf
            #pragma unroll
            for (int i = 0; i < 4; i++)
                stage16(bsrc + (size_t)(kc + 1) * (16 * 512) + i * 512,
                        &Blds[(kc + 1) & 1][(w * 4 + i) * 512]);
        }

        bf16x8 af0, af1;
        if (kc < 8) {
            floatx4 s00 = hp00 + ha0, s01 = hp01 + ha1;
            floatx4 s10 = hp10 + ha0, s11 = hp11 + ha1;
            if (kc < 7) {                 // prefetch next chunk's A inputs
                hp00 = *(const floatx4*)(hp0_ptr + (kc + 1) * 32);
                hp01 = *(const floatx4*)(hp0_ptr + (kc + 1) * 32 + 4);
                hp10 = *(const floatx4*)(hp1_ptr + (kc + 1) * 32);
                hp11 = *(const floatx4*)(hp1_ptr + (kc + 1) * 32 + 4);
                ha0  = *(const floatx4*)(ha_ptr  + (kc + 1) * 32);
                ha1  = *(const floatx4*)(ha_ptr  + (kc + 1) * 32 + 4);
            }
            #pragma unroll
            for (int j = 0; j < 4; j++) {
                af0[j]     = (__bf16)tanh_pre(s00[j]);
                af0[4 + j] = (__bf16)tanh_pre(s01[j]);
                af1[j]     = (__bf16)tanh_pre(s10[j]);
                af1[4 + j] = (__bf16)tanh_pre(s11[j]);
            }
        } else {                          // folded chunk: A=[bs(4),1,0...]
            af0 = bf16x8{}; af1 = bf16x8{};
            if (quad == 0) {
                #pragma unroll
                for (int j = 0; j < 4; j++) {
                    af0[j] = (__bf16)bsv0[j];
                    af1[j] = (__bf16)bsv1[j];
                }
                af0[4] = (__bf16)1.0f;
                af1[4] = (__bf16)1.0f;
            }
        }

        #pragma unroll
        for (int ct = 0; ct < 16; ct++) {
            bf16x8 bv = *(const bf16x8*)&Blds[kc & 1][ct * 512 + lane * 8];
            acc0[ct] = __builtin_amdgcn_mfma_f32_16x16x32_bf16(af0, bv, acc0[ct], 0, 0, 0);
            acc1[ct] = __builtin_amdgcn_mfma_f32_16x16x32_bf16(af1, bv, acc1[ct], 0, 0, 0);
        }
    }

    // ---- epilogue: tanh(acc) . Wout, reduce over 16 cols within quad
    float rs0[4] = {0.f, 0.f, 0.f, 0.f}, rs1[4] = {0.f, 0.f, 0.f, 0.f};
    #pragma unroll
    for (int ct = 0; ct < 16; ct++) {
        const float woc = Wout[n * 256 + ct * 16 + col16];
        #pragma unroll
        for (int reg = 0; reg < 4; reg++) {
            rs0[reg] += tanh_pre(acc0[ct][reg]) * woc;
            rs1[reg] += tanh_pre(acc1[ct][reg]) * woc;
        }
    }
    #pragma unroll
    for (int reg = 0; reg < 4; reg++) {
        rs0[reg] += __shfl_xor(rs0[reg], 1);
        rs0[reg] += __shfl_xor(rs0[reg], 2);
        rs0[reg] += __shfl_xor(rs0[reg], 4);
        rs0[reg] += __shfl_xor(rs0[reg], 8);
        rs1[reg] += __shfl_xor(rs1[reg], 1);
        rs1[reg] += __shfl_xor(rs1[reg], 2);
        rs1[reg] += __shfl_xor(rs1[reg], 4);
        rs1[reg] += __shfl_xor(rs1[reg], 8);
    }
    if (col16 == 0) {
        #pragma unroll
        for (int reg = 0; reg < 4; reg++) {
            const int r0 = w * 32 + quad * 4 + reg;           // frag 0 row
            int p = p0 + (r0 >> 3), a = a0 + (r0 & 7);
            out[((size_t)(b * LSEQ + p) * NCASE + n) * LSEQ + a] = rs0[reg];
            const int r1 = r0 + 16;                           // frag 1 row
            p = p0 + (r1 >> 3); a = a0 + (r1 & 7);
            out[((size_t)(b * LSEQ + p) * NCASE + n) * LSEQ + a] = rs1[reg];
        }
    }
}

// ---------------------------------------------------------------------------
extern "C" void kernel_launch(void* const* d_in, const int* in_sizes, int n_in,
                              void* d_out, int out_size, void* d_ws, size_t ws_size,
                              hipStream_t stream) {
    const float* seq  = (const float*)d_in[0];
    const float* bsc  = (const float*)d_in[1];
    const float* Wp   = (const float*)d_in[2];
    const float* bp   = (const float*)d_in[3];
    const float* Wa   = (const float*)d_in[4];
    const float* ba   = (const float*)d_in[5];
    const float* Wmid = (const float*)d_in[6];
    const float* bmid = (const float*)d_in[7];
    const float* Wout = (const float*)d_in[8];
    float* out = (float*)d_out;

    // workspace layout (16B-aligned):
    char* ws = (char*)d_ws;
    bf16x8* seq_hi = (bf16x8*)(ws);                    //   589,824 B
    bf16x8* seq_lo = (bf16x8*)(ws +  589824);          //   589,824 B
    bf16x8* W_hi   = (bf16x8*)(ws + 1179648);          // 1,966,080 B
    bf16x8* W_lo   = (bf16x8*)(ws + 3145728);          // 1,966,080 B
    bf16x8* Bpack  = (bf16x8*)(ws + 5111808);          //   589,824 B
    float*  lin    = (float*) (ws + 5701632);          // 1,966,080 B  (fp32)

    pack_all<<<768, 256, 0, stream>>>(seq, Wp, Wa, Wmid, bmid,
                                      seq_hi, seq_lo, W_hi, W_lo, Bpack);
    lin_mfma<<<dim3(24, 20), 64, 0, stream>>>(seq_hi, seq_lo, W_hi, W_lo,
                                              bp, ba, lin);
    refine_main<<<dim3(288, NCASE, BATCH), 256, 0, stream>>>(
        lin, bsc, Wout, (const __bf16*)Bpack, out);
}